// Round 5
// baseline (86.052 us; speedup 1.0000x reference)
//
#include <hip/hip_runtime.h>

// PIQuantumDQN: 4-qubit, 5-layer re-uploading circuit, B=524288 samples.
// One thread per sample; 16-amplitude complex state in registers.
// wire q (0 = MSB) <-> bit (3-q) of the flat index, so mask(q) = 8 >> q.
// R5: batch-uniform work (weight sincos, W, b) moved to a one-block setup
// kernel writing d_ws; main kernel reads it at constant offsets -> s_load
// into SGPRs (zero VALU, no readfirstlane, no redundant transcendentals).
// Per-sample RY trig uses raw v_sin/v_cos in revolutions (xn*0.25, |.|<=0.25,
// no range reduction) instead of __sincosf's mul(1/2pi)+fract.

template<int MASK>
__device__ __forceinline__ void apply_ry(float re[16], float im[16], float c, float s) {
#pragma unroll
    for (int i0 = 0; i0 < 16; ++i0) {
        if (i0 & MASK) continue;
        const int i1 = i0 | MASK;
        float r0 = re[i0], r1 = re[i1];
        float m0 = im[i0], m1 = im[i1];
        re[i0] = c * r0 - s * r1;
        re[i1] = s * r0 + c * r1;
        im[i0] = c * m0 - s * m1;
        im[i1] = s * m0 + c * m1;
    }
}

// RX(t): a0' = c*a0 - i*s*a1 ; a1' = -i*s*a0 + c*a1   (c=cos t/2, s=sin t/2)
template<int MASK>
__device__ __forceinline__ void apply_rx(float re[16], float im[16], float c, float s) {
#pragma unroll
    for (int i0 = 0; i0 < 16; ++i0) {
        if (i0 & MASK) continue;
        const int i1 = i0 | MASK;
        float r0 = re[i0], r1 = re[i1];
        float m0 = im[i0], m1 = im[i1];
        re[i0] = c * r0 + s * m1;
        im[i0] = c * m0 - s * r1;
        re[i1] = c * r1 + s * m0;
        im[i1] = c * m1 - s * r0;
    }
}

template<int CMASK, int TMASK>
__device__ __forceinline__ void apply_cnot(float re[16], float im[16]) {
#pragma unroll
    for (int i = 0; i < 16; ++i) {
        if ((i & CMASK) && !(i & TMASK)) {
            const int j = i | TMASK;
            float tr = re[i]; re[i] = re[j]; re[j] = tr;
            float ti = im[i]; im[i] = im[j]; im[j] = ti;
        }
    }
}

// uni layout in d_ws: [0..19] cos(w/2), [20..39] sin(w/2), [40..47] W, [48..49] b
__global__ void qdqn_setup(const float* __restrict__ weights,
                           const float* __restrict__ Wm,
                           const float* __restrict__ bv,
                           float* __restrict__ uni) {
    const int t = threadIdx.x;
    if (t < 20) {
        float s, c;
        __sincosf(0.5f * weights[t], &s, &c);
        uni[t] = c;
        uni[20 + t] = s;
    } else if (t < 28) {
        uni[20 + t] = Wm[t - 20];      // uni[40..47]
    } else if (t < 30) {
        uni[20 + t] = bv[t - 28];      // uni[48..49]
    }
}

__global__ __launch_bounds__(256) void qdqn_kernel(
    const float* __restrict__ x,       // (B,4) fp32
    const float* __restrict__ uni,     // 50 uniform coefficients (see layout)
    float2* __restrict__ out,          // (B,2) fp32
    int B)
{
    // ---- uniforms: constant offsets off a uniform pointer -> s_load/SGPRs ----
    float wc[20], ws[20];
#pragma unroll
    for (int k = 0; k < 20; ++k) { wc[k] = uni[k]; ws[k] = uni[20 + k]; }
    float Wu[8];
#pragma unroll
    for (int k = 0; k < 8; ++k) Wu[k] = uni[40 + k];
    const float b0u = uni[48];
    const float b1u = uni[49];

    const int b = blockIdx.x * blockDim.x + threadIdx.x;
    if (b >= B) return;

    // ---- load x (16B coalesced), RY half-angle cos/sin (same every layer) ----
    // sin(xn*pi/2) = v_sin(xn*0.25 revolutions); |xn|<=1 -> |rev|<=0.25, no reduction.
    const float4 xraw = ((const float4*)x)[b];
    float xv[4] = { xraw.x, xraw.y, xraw.z, xraw.w };
    const float inv_bounds4[4] = { 0.25f / 4.8f, 0.25f / 4.0f, 0.25f / 0.418f, 0.25f / 4.0f };
    float rc[4], rs[4];
#pragma unroll
    for (int q = 0; q < 4; ++q) {
        float rev = xv[q] * inv_bounds4[q];
        rev = fminf(fmaxf(rev, -0.25f), 0.25f);
        rs[q] = __builtin_amdgcn_sinf(rev);
        rc[q] = __builtin_amdgcn_cosf(rev);
    }

    // ---- layer 0 fast path: state separable until the first CNOT ----
    // per wire: RX(w)*RY(a)|0> = (alpha, beta),
    //   alpha = (c_w c_a, -s_w s_a), beta = (c_w s_a, -s_w c_a)
    float ar[4], ai[4], br[4], bi[4];
#pragma unroll
    for (int q = 0; q < 4; ++q) {
        ar[q] =  wc[q] * rc[q];
        ai[q] = -ws[q] * rs[q];
        br[q] =  wc[q] * rs[q];
        bi[q] = -ws[q] * rc[q];
    }
    // tensor product, wire 0 = MSB
    float t2r[4], t2i[4];                     // wires 0,1
#pragma unroll
    for (int i = 0; i < 4; ++i) {
        float xr = (i & 2) ? br[0] : ar[0], xi = (i & 2) ? bi[0] : ai[0];
        float yr = (i & 1) ? br[1] : ar[1], yi = (i & 1) ? bi[1] : ai[1];
        t2r[i] = xr * yr - xi * yi;
        t2i[i] = xr * yi + xi * yr;
    }
    float t3r[8], t3i[8];                     // + wire 2
#pragma unroll
    for (int i = 0; i < 8; ++i) {
        float xr = t2r[i >> 1], xi = t2i[i >> 1];
        float yr = (i & 1) ? br[2] : ar[2], yi = (i & 1) ? bi[2] : ai[2];
        t3r[i] = xr * yr - xi * yi;
        t3i[i] = xr * yi + xi * yr;
    }
    float re[16], im[16];                     // + wire 3
#pragma unroll
    for (int i = 0; i < 16; ++i) {
        float xr = t3r[i >> 1], xi = t3i[i >> 1];
        float yr = (i & 1) ? br[3] : ar[3], yi = (i & 1) ? bi[3] : ai[3];
        re[i] = xr * yr - xi * yi;
        im[i] = xr * yi + xi * yr;
    }
    // layer 0 CNOT ring (pure register renaming, zero instructions)
    apply_cnot<8, 4>(re, im);
    apply_cnot<4, 2>(re, im);
    apply_cnot<2, 1>(re, im);
    apply_cnot<1, 8>(re, im);

    // ---- layers 1..4 ----
#pragma unroll
    for (int l = 1; l < 5; ++l) {
        apply_ry<8>(re, im, rc[0], rs[0]);
        apply_ry<4>(re, im, rc[1], rs[1]);
        apply_ry<2>(re, im, rc[2], rs[2]);
        apply_ry<1>(re, im, rc[3], rs[3]);
        apply_rx<8>(re, im, wc[l * 4 + 0], ws[l * 4 + 0]);
        apply_rx<4>(re, im, wc[l * 4 + 1], ws[l * 4 + 1]);
        apply_rx<2>(re, im, wc[l * 4 + 2], ws[l * 4 + 2]);
        apply_rx<1>(re, im, wc[l * 4 + 3], ws[l * 4 + 3]);
        apply_cnot<8, 4>(re, im);
        apply_cnot<4, 2>(re, im);
        apply_cnot<2, 1>(re, im);
        apply_cnot<1, 8>(re, im);
    }

    // ---- probs -> <Z_q> via sign tree -> linear layer ----
    float p[16];
#pragma unroll
    for (int i = 0; i < 16; ++i) p[i] = re[i] * re[i] + im[i] * im[i];
    float t[8];
#pragma unroll
    for (int i = 0; i < 8; ++i) t[i] = p[2 * i] + p[2 * i + 1];
    float u[4];
#pragma unroll
    for (int i = 0; i < 4; ++i) u[i] = t[2 * i] + t[2 * i + 1];
    const float z0 = (u[0] + u[1]) - (u[2] + u[3]);             // wire 0 (bit 3)
    const float z1 = (u[0] - u[1]) + (u[2] - u[3]);             // wire 1 (bit 2)
    const float z2 = (t[0] - t[1]) + (t[2] - t[3])
                   + (t[4] - t[5]) + (t[6] - t[7]);             // wire 2 (bit 1)
    const float z3 = ((p[0] - p[1]) + (p[2] - p[3]))
                   + ((p[4] - p[5]) + (p[6] - p[7]))
                   + ((p[8] - p[9]) + (p[10] - p[11]))
                   + ((p[12] - p[13]) + (p[14] - p[15]));       // wire 3 (bit 0)

    float o0 = b0u, o1 = b1u;
    o0 = fmaf(Wu[0], z0, o0); o0 = fmaf(Wu[1], z1, o0);
    o0 = fmaf(Wu[2], z2, o0); o0 = fmaf(Wu[3], z3, o0);
    o1 = fmaf(Wu[4], z0, o1); o1 = fmaf(Wu[5], z1, o1);
    o1 = fmaf(Wu[6], z2, o1); o1 = fmaf(Wu[7], z3, o1);

    out[b] = make_float2(o0, o1);   // 8B coalesced f32 store
}

extern "C" void kernel_launch(void* const* d_in, const int* in_sizes, int n_in,
                              void* d_out, int out_size, void* d_ws, size_t ws_size,
                              hipStream_t stream) {
    const float* x  = (const float*)d_in[0];
    const float* w  = (const float*)d_in[1];
    const float* Wm = (const float*)d_in[2];
    const float* bv = (const float*)d_in[3];
    float* uni = (float*)d_ws;          // 50 floats of scratch
    float2* out = (float2*)d_out;

    qdqn_setup<<<1, 64, 0, stream>>>(w, Wm, bv, uni);

    const int B = in_sizes[0] / 4;
    dim3 grid((B + 255) / 256), block(256);
    qdqn_kernel<<<grid, block, 0, stream>>>(x, uni, out, B);
}

// Round 6
// 83.285 us; speedup vs baseline: 1.0332x; 1.0332x over previous
//
#include <hip/hip_runtime.h>

// PIQuantumDQN: 4-qubit, 5-layer re-uploading circuit, B=524288 samples.
// R6: back to a single kernel (no setup dispatch); batch-uniform coefficients
// computed once per wave with v_sin/v_cos in revolutions and pinned to SGPRs
// via readfirstlane. TWO samples per thread: amortizes the wave prologue
// (uniform setup, s_load/vmcnt waits), doubles independent FMA chains, and
// makes the epilogue store one coalesced float4 per thread.
// wire q (0 = MSB) <-> bit (3-q) of the flat index, so mask(q) = 8 >> q.

__device__ __forceinline__ float rfl(float v) {
    return __uint_as_float(__builtin_amdgcn_readfirstlane(__float_as_uint(v)));
}

template<int MASK>
__device__ __forceinline__ void apply_ry(float (&re)[16], float (&im)[16], float c, float s) {
#pragma unroll
    for (int i0 = 0; i0 < 16; ++i0) {
        if (i0 & MASK) continue;
        const int i1 = i0 | MASK;
        float r0 = re[i0], r1 = re[i1];
        float m0 = im[i0], m1 = im[i1];
        re[i0] = c * r0 - s * r1;
        re[i1] = s * r0 + c * r1;
        im[i0] = c * m0 - s * m1;
        im[i1] = s * m0 + c * m1;
    }
}

// RX(t): a0' = c*a0 - i*s*a1 ; a1' = -i*s*a0 + c*a1   (c=cos t/2, s=sin t/2)
template<int MASK>
__device__ __forceinline__ void apply_rx(float (&re)[16], float (&im)[16], float c, float s) {
#pragma unroll
    for (int i0 = 0; i0 < 16; ++i0) {
        if (i0 & MASK) continue;
        const int i1 = i0 | MASK;
        float r0 = re[i0], r1 = re[i1];
        float m0 = im[i0], m1 = im[i1];
        re[i0] = c * r0 + s * m1;
        im[i0] = c * m0 - s * r1;
        re[i1] = c * r1 + s * m0;
        im[i1] = c * m1 - s * r0;
    }
}

template<int CMASK, int TMASK>
__device__ __forceinline__ void apply_cnot(float (&re)[16], float (&im)[16]) {
#pragma unroll
    for (int i = 0; i < 16; ++i) {
        if ((i & CMASK) && !(i & TMASK)) {
            const int j = i | TMASK;
            float tr = re[i]; re[i] = re[j]; re[j] = tr;
            float ti = im[i]; im[i] = im[j]; im[j] = ti;
        }
    }
}

struct Uni {
    float wc[20], ws[20], Wu[8], b0, b1;
};

// One full sample: x4 -> (o0, o1)
__device__ __forceinline__ void run_sample(const float4& xraw, const Uni& U,
                                           float& o0, float& o1) {
    // RY half-angle cos/sin in revolutions: sin(xn*pi/2) = v_sin(xn*0.25 rev)
    float rc[4], rs[4];
    const float inv_bounds4[4] = { 0.25f / 4.8f, 0.25f / 4.0f, 0.25f / 0.418f, 0.25f / 4.0f };
    float xv[4] = { xraw.x, xraw.y, xraw.z, xraw.w };
#pragma unroll
    for (int q = 0; q < 4; ++q) {
        float rev = xv[q] * inv_bounds4[q];
        rev = fminf(fmaxf(rev, -0.25f), 0.25f);
        rs[q] = __builtin_amdgcn_sinf(rev);
        rc[q] = __builtin_amdgcn_cosf(rev);
    }

    // layer 0: separable until the first CNOT. RX(w)RY(a)|0> = (alpha, beta)
    float ar[4], ai[4], br[4], bi[4];
#pragma unroll
    for (int q = 0; q < 4; ++q) {
        ar[q] =  U.wc[q] * rc[q];
        ai[q] = -U.ws[q] * rs[q];
        br[q] =  U.wc[q] * rs[q];
        bi[q] = -U.ws[q] * rc[q];
    }
    float t2r[4], t2i[4];
#pragma unroll
    for (int i = 0; i < 4; ++i) {
        float xr = (i & 2) ? br[0] : ar[0], xi = (i & 2) ? bi[0] : ai[0];
        float yr = (i & 1) ? br[1] : ar[1], yi = (i & 1) ? bi[1] : ai[1];
        t2r[i] = xr * yr - xi * yi;
        t2i[i] = xr * yi + xi * yr;
    }
    float t3r[8], t3i[8];
#pragma unroll
    for (int i = 0; i < 8; ++i) {
        float xr = t2r[i >> 1], xi = t2i[i >> 1];
        float yr = (i & 1) ? br[2] : ar[2], yi = (i & 1) ? bi[2] : ai[2];
        t3r[i] = xr * yr - xi * yi;
        t3i[i] = xr * yi + xi * yr;
    }
    float re[16], im[16];
#pragma unroll
    for (int i = 0; i < 16; ++i) {
        float xr = t3r[i >> 1], xi = t3i[i >> 1];
        float yr = (i & 1) ? br[3] : ar[3], yi = (i & 1) ? bi[3] : ai[3];
        re[i] = xr * yr - xi * yi;
        im[i] = xr * yi + xi * yr;
    }
    apply_cnot<8, 4>(re, im);
    apply_cnot<4, 2>(re, im);
    apply_cnot<2, 1>(re, im);
    apply_cnot<1, 8>(re, im);

    // layers 1..4
#pragma unroll
    for (int l = 1; l < 5; ++l) {
        apply_ry<8>(re, im, rc[0], rs[0]);
        apply_ry<4>(re, im, rc[1], rs[1]);
        apply_ry<2>(re, im, rc[2], rs[2]);
        apply_ry<1>(re, im, rc[3], rs[3]);
        apply_rx<8>(re, im, U.wc[l * 4 + 0], U.ws[l * 4 + 0]);
        apply_rx<4>(re, im, U.wc[l * 4 + 1], U.ws[l * 4 + 1]);
        apply_rx<2>(re, im, U.wc[l * 4 + 2], U.ws[l * 4 + 2]);
        apply_rx<1>(re, im, U.wc[l * 4 + 3], U.ws[l * 4 + 3]);
        apply_cnot<8, 4>(re, im);
        apply_cnot<4, 2>(re, im);
        apply_cnot<2, 1>(re, im);
        apply_cnot<1, 8>(re, im);
    }

    // probs -> <Z_q> sign tree -> linear layer
    float p[16];
#pragma unroll
    for (int i = 0; i < 16; ++i) p[i] = re[i] * re[i] + im[i] * im[i];
    float t[8];
#pragma unroll
    for (int i = 0; i < 8; ++i) t[i] = p[2 * i] + p[2 * i + 1];
    float u[4];
#pragma unroll
    for (int i = 0; i < 4; ++i) u[i] = t[2 * i] + t[2 * i + 1];
    const float z0 = (u[0] + u[1]) - (u[2] + u[3]);
    const float z1 = (u[0] - u[1]) + (u[2] - u[3]);
    const float z2 = (t[0] - t[1]) + (t[2] - t[3])
                   + (t[4] - t[5]) + (t[6] - t[7]);
    const float z3 = ((p[0] - p[1]) + (p[2] - p[3]))
                   + ((p[4] - p[5]) + (p[6] - p[7]))
                   + ((p[8] - p[9]) + (p[10] - p[11]))
                   + ((p[12] - p[13]) + (p[14] - p[15]));

    o0 = U.b0; o1 = U.b1;
    o0 = fmaf(U.Wu[0], z0, o0); o0 = fmaf(U.Wu[1], z1, o0);
    o0 = fmaf(U.Wu[2], z2, o0); o0 = fmaf(U.Wu[3], z3, o0);
    o1 = fmaf(U.Wu[4], z0, o1); o1 = fmaf(U.Wu[5], z1, o1);
    o1 = fmaf(U.Wu[6], z2, o1); o1 = fmaf(U.Wu[7], z3, o1);
}

__global__ __launch_bounds__(256) void qdqn_kernel(
    const float* __restrict__ x,        // (B,4) fp32
    const float* __restrict__ weights,  // (5,4) fp32
    const float* __restrict__ Wm,       // (2,4) fp32
    const float* __restrict__ bv,       // (2,)  fp32
    float4* __restrict__ out,           // (B/2,4): two float2 outputs packed
    int Bh)                             // B/2 threads
{
    // ---- batch-uniform coefficients -> SGPRs (rfl-pinned), in revolutions ----
    // cos/sin(w/2): rev = w * (1/(4*pi)); w in [0, 2*pi] -> rev in [0, 0.5]
    Uni U;
    const float INV_4PI = 0.07957747154594767f;
#pragma unroll
    for (int k = 0; k < 20; ++k) {
        float rev = weights[k] * INV_4PI;       // uniform address -> scalar load
        U.wc[k] = rfl(__builtin_amdgcn_cosf(rev));
        U.ws[k] = rfl(__builtin_amdgcn_sinf(rev));
    }
#pragma unroll
    for (int k = 0; k < 8; ++k) U.Wu[k] = rfl(Wm[k]);
    U.b0 = rfl(bv[0]);
    U.b1 = rfl(bv[1]);

    const int t = blockIdx.x * blockDim.x + threadIdx.x;
    if (t >= Bh) return;

    // two consecutive samples: 2t and 2t+1
    const float4 xA = ((const float4*)x)[2 * t];
    const float4 xB = ((const float4*)x)[2 * t + 1];

    float a0, a1, c0, c1;
    run_sample(xA, U, a0, a1);
    run_sample(xB, U, c0, c1);

    out[t] = make_float4(a0, a1, c0, c1);   // 16B coalesced store
}

extern "C" void kernel_launch(void* const* d_in, const int* in_sizes, int n_in,
                              void* d_out, int out_size, void* d_ws, size_t ws_size,
                              hipStream_t stream) {
    const float* x  = (const float*)d_in[0];
    const float* w  = (const float*)d_in[1];
    const float* Wm = (const float*)d_in[2];
    const float* bv = (const float*)d_in[3];
    float4* out = (float4*)d_out;

    const int B  = in_sizes[0] / 4;
    const int Bh = B / 2;                       // B is even (524288)
    dim3 grid((Bh + 255) / 256), block(256);
    qdqn_kernel<<<grid, block, 0, stream>>>(x, w, Wm, bv, out, Bh);
}

// Round 7
// 79.006 us; speedup vs baseline: 1.0892x; 1.0542x over previous
//
#include <hip/hip_runtime.h>

// PIQuantumDQN: 4-qubit, 5-layer re-uploading circuit, B=524288 samples.
// R7: two samples per thread, state packed as <2 x float> (sample A in .x,
// sample B in .y) so every gate op is an elementwise 2-vector mul/fma ->
// LLVM lowers to v_pk_mul_f32 / v_pk_fma_f32 on gfx950. This tests whether
// packed f32 is full-rate (2x FLOP) or two-pass (neutral) on CDNA4 — the
// docs have no measurement for it.
// wire q (0 = MSB) <-> bit (3-q) of the flat index, so mask(q) = 8 >> q.

typedef float v2f __attribute__((ext_vector_type(2)));

__device__ __forceinline__ v2f splat(float x) { return (v2f){x, x}; }

__device__ __forceinline__ float rfl(float v) {
    return __uint_as_float(__builtin_amdgcn_readfirstlane(__float_as_uint(v)));
}

template<int MASK>
__device__ __forceinline__ void apply_ry(v2f (&re)[16], v2f (&im)[16], v2f c, v2f s) {
#pragma unroll
    for (int i0 = 0; i0 < 16; ++i0) {
        if (i0 & MASK) continue;
        const int i1 = i0 | MASK;
        v2f r0 = re[i0], r1 = re[i1];
        v2f m0 = im[i0], m1 = im[i1];
        re[i0] = c * r0 - s * r1;
        re[i1] = s * r0 + c * r1;
        im[i0] = c * m0 - s * m1;
        im[i1] = s * m0 + c * m1;
    }
}

// RX(t): a0' = c*a0 - i*s*a1 ; a1' = -i*s*a0 + c*a1   (c=cos t/2, s=sin t/2)
template<int MASK>
__device__ __forceinline__ void apply_rx(v2f (&re)[16], v2f (&im)[16], v2f c, v2f s) {
#pragma unroll
    for (int i0 = 0; i0 < 16; ++i0) {
        if (i0 & MASK) continue;
        const int i1 = i0 | MASK;
        v2f r0 = re[i0], r1 = re[i1];
        v2f m0 = im[i0], m1 = im[i1];
        re[i0] = c * r0 + s * m1;
        im[i0] = c * m0 - s * r1;
        re[i1] = c * r1 + s * m0;
        im[i1] = c * m1 - s * r0;
    }
}

template<int CMASK, int TMASK>
__device__ __forceinline__ void apply_cnot(v2f (&re)[16], v2f (&im)[16]) {
#pragma unroll
    for (int i = 0; i < 16; ++i) {
        if ((i & CMASK) && !(i & TMASK)) {
            const int j = i | TMASK;
            v2f tr = re[i]; re[i] = re[j]; re[j] = tr;
            v2f ti = im[i]; im[i] = im[j]; im[j] = ti;
        }
    }
}

__global__ __launch_bounds__(256) void qdqn_kernel(
    const float* __restrict__ x,        // (B,4) fp32
    const float* __restrict__ weights,  // (5,4) fp32
    const float* __restrict__ Wm,       // (2,4) fp32
    const float* __restrict__ bv,       // (2,)  fp32
    float4* __restrict__ out,           // (B/2,4): two float2 outputs packed
    int Bh)                             // B/2 threads
{
    // ---- batch-uniform coefficients -> SGPRs (rfl-pinned), revolutions form ----
    float wc[20], ws[20], Wu[8];
    const float INV_4PI = 0.07957747154594767f;   // w/2 rad = w*(1/4pi) rev
#pragma unroll
    for (int k = 0; k < 20; ++k) {
        float rev = weights[k] * INV_4PI;         // uniform -> scalar load
        wc[k] = rfl(__builtin_amdgcn_cosf(rev));
        ws[k] = rfl(__builtin_amdgcn_sinf(rev));
    }
#pragma unroll
    for (int k = 0; k < 8; ++k) Wu[k] = rfl(Wm[k]);
    const float b0u = rfl(bv[0]);
    const float b1u = rfl(bv[1]);

    const int t = blockIdx.x * blockDim.x + threadIdx.x;
    if (t >= Bh) return;

    // ---- load two consecutive samples, pack component-wise into v2f ----
    const float4 xA = ((const float4*)x)[2 * t];
    const float4 xB = ((const float4*)x)[2 * t + 1];
    v2f xv[4] = { (v2f){xA.x, xB.x}, (v2f){xA.y, xB.y},
                  (v2f){xA.z, xB.z}, (v2f){xA.w, xB.w} };

    // RY half-angle cos/sin: sin(xn*pi/2) = v_sin(xn*0.25 rev), |rev|<=0.25
    const float inv_bounds4[4] = { 0.25f / 4.8f, 0.25f / 4.0f, 0.25f / 0.418f, 0.25f / 4.0f };
    v2f rc[4], rs[4];
#pragma unroll
    for (int q = 0; q < 4; ++q) {
        v2f rev = xv[q] * splat(inv_bounds4[q]);
        float ra = fminf(fmaxf(rev.x, -0.25f), 0.25f);
        float rb = fminf(fmaxf(rev.y, -0.25f), 0.25f);
        rs[q] = (v2f){ __builtin_amdgcn_sinf(ra), __builtin_amdgcn_sinf(rb) };
        rc[q] = (v2f){ __builtin_amdgcn_cosf(ra), __builtin_amdgcn_cosf(rb) };
    }

    // ---- layer 0: separable until the first CNOT. RX(w)RY(a)|0> = (alpha,beta)
    //   alpha = (c_w c_a, -s_w s_a), beta = (c_w s_a, -s_w c_a)
    v2f ar[4], ai[4], br[4], bi[4];
#pragma unroll
    for (int q = 0; q < 4; ++q) {
        v2f cw = splat(wc[q]), sw = splat(ws[q]);
        ar[q] =  cw * rc[q];
        ai[q] = -sw * rs[q];
        br[q] =  cw * rs[q];
        bi[q] = -sw * rc[q];
    }
    // tensor product, wire 0 = MSB
    v2f t2r[4], t2i[4];
#pragma unroll
    for (int i = 0; i < 4; ++i) {
        v2f xr = (i & 2) ? br[0] : ar[0], xi = (i & 2) ? bi[0] : ai[0];
        v2f yr = (i & 1) ? br[1] : ar[1], yi = (i & 1) ? bi[1] : ai[1];
        t2r[i] = xr * yr - xi * yi;
        t2i[i] = xr * yi + xi * yr;
    }
    v2f t3r[8], t3i[8];
#pragma unroll
    for (int i = 0; i < 8; ++i) {
        v2f xr = t2r[i >> 1], xi = t2i[i >> 1];
        v2f yr = (i & 1) ? br[2] : ar[2], yi = (i & 1) ? bi[2] : ai[2];
        t3r[i] = xr * yr - xi * yi;
        t3i[i] = xr * yi + xi * yr;
    }
    v2f re[16], im[16];
#pragma unroll
    for (int i = 0; i < 16; ++i) {
        v2f xr = t3r[i >> 1], xi = t3i[i >> 1];
        v2f yr = (i & 1) ? br[3] : ar[3], yi = (i & 1) ? bi[3] : ai[3];
        re[i] = xr * yr - xi * yi;
        im[i] = xr * yi + xi * yr;
    }
    // layer 0 CNOT ring (register renaming, zero instructions)
    apply_cnot<8, 4>(re, im);
    apply_cnot<4, 2>(re, im);
    apply_cnot<2, 1>(re, im);
    apply_cnot<1, 8>(re, im);

    // ---- layers 1..4 ----
#pragma unroll
    for (int l = 1; l < 5; ++l) {
        apply_ry<8>(re, im, rc[0], rs[0]);
        apply_ry<4>(re, im, rc[1], rs[1]);
        apply_ry<2>(re, im, rc[2], rs[2]);
        apply_ry<1>(re, im, rc[3], rs[3]);
        apply_rx<8>(re, im, splat(wc[l * 4 + 0]), splat(ws[l * 4 + 0]));
        apply_rx<4>(re, im, splat(wc[l * 4 + 1]), splat(ws[l * 4 + 1]));
        apply_rx<2>(re, im, splat(wc[l * 4 + 2]), splat(ws[l * 4 + 2]));
        apply_rx<1>(re, im, splat(wc[l * 4 + 3]), splat(ws[l * 4 + 3]));
        apply_cnot<8, 4>(re, im);
        apply_cnot<4, 2>(re, im);
        apply_cnot<2, 1>(re, im);
        apply_cnot<1, 8>(re, im);
    }

    // ---- probs -> <Z_q> sign tree -> linear layer (all packed) ----
    v2f p[16];
#pragma unroll
    for (int i = 0; i < 16; ++i) p[i] = re[i] * re[i] + im[i] * im[i];
    v2f tt[8];
#pragma unroll
    for (int i = 0; i < 8; ++i) tt[i] = p[2 * i] + p[2 * i + 1];
    v2f u[4];
#pragma unroll
    for (int i = 0; i < 4; ++i) u[i] = tt[2 * i] + tt[2 * i + 1];
    const v2f z0 = (u[0] + u[1]) - (u[2] + u[3]);               // wire 0 (bit 3)
    const v2f z1 = (u[0] - u[1]) + (u[2] - u[3]);               // wire 1 (bit 2)
    const v2f z2 = (tt[0] - tt[1]) + (tt[2] - tt[3])
                 + (tt[4] - tt[5]) + (tt[6] - tt[7]);           // wire 2 (bit 1)
    const v2f z3 = ((p[0] - p[1]) + (p[2] - p[3]))
                 + ((p[4] - p[5]) + (p[6] - p[7]))
                 + ((p[8] - p[9]) + (p[10] - p[11]))
                 + ((p[12] - p[13]) + (p[14] - p[15]));         // wire 3 (bit 0)

    v2f o0 = splat(b0u), o1 = splat(b1u);
    o0 = splat(Wu[0]) * z0 + o0; o0 = splat(Wu[1]) * z1 + o0;
    o0 = splat(Wu[2]) * z2 + o0; o0 = splat(Wu[3]) * z3 + o0;
    o1 = splat(Wu[4]) * z0 + o1; o1 = splat(Wu[5]) * z1 + o1;
    o1 = splat(Wu[6]) * z2 + o1; o1 = splat(Wu[7]) * z3 + o1;

    out[t] = make_float4(o0.x, o1.x, o0.y, o1.y);   // 16B coalesced store
}

extern "C" void kernel_launch(void* const* d_in, const int* in_sizes, int n_in,
                              void* d_out, int out_size, void* d_ws, size_t ws_size,
                              hipStream_t stream) {
    const float* x  = (const float*)d_in[0];
    const float* w  = (const float*)d_in[1];
    const float* Wm = (const float*)d_in[2];
    const float* bv = (const float*)d_in[3];
    float4* out = (float4*)d_out;

    const int B  = in_sizes[0] / 4;
    const int Bh = B / 2;                       // B is even (524288)
    dim3 grid((Bh + 255) / 256), block(256);
    qdqn_kernel<<<grid, block, 0, stream>>>(x, w, Wm, bv, out, Bh);
}

// Round 8
// 76.921 us; speedup vs baseline: 1.1187x; 1.0271x over previous
//
#include <hip/hip_runtime.h>

// PIQuantumDQN: 4-qubit, 5-layer re-uploading circuit, B=524288 samples.
// R8: RX gates in TANGENT form (FMA-only, 4 inst/pair instead of 8); the
// deferred cos(w/2) factors are batch-uniform, so the total scale
// S = prod_{l,q} cos(w/2) folds into the output weights: Wu' = Wu * S^2.
// RY stays in standard form (cos hits 0 exactly at the clip boundary).
// Two samples per thread packed as <2 x float> (v_pk_* issue compression;
// measured R7: pk f32 is 2-pass on gfx950, gains come from issue slots).
// wire q (0 = MSB) <-> bit (3-q) of the flat index, so mask(q) = 8 >> q.

typedef float v2f __attribute__((ext_vector_type(2)));

__device__ __forceinline__ v2f splat(float x) { return (v2f){x, x}; }

__device__ __forceinline__ float rfl(float v) {
    return __uint_as_float(__builtin_amdgcn_readfirstlane(__float_as_uint(v)));
}

template<int MASK>
__device__ __forceinline__ void apply_ry(v2f (&re)[16], v2f (&im)[16], v2f c, v2f s) {
#pragma unroll
    for (int i0 = 0; i0 < 16; ++i0) {
        if (i0 & MASK) continue;
        const int i1 = i0 | MASK;
        v2f r0 = re[i0], r1 = re[i1];
        v2f m0 = im[i0], m1 = im[i1];
        re[i0] = c * r0 - s * r1;
        re[i1] = s * r0 + c * r1;
        im[i0] = c * m0 - s * m1;
        im[i1] = s * m0 + c * m1;
    }
}

// RX tangent form (t = tan(w/2)); true output = cos(w/2) * (this output).
// out0 = r0 + t*m1 ; out0i = m0 - t*r1 ; out1 = r1 + t*m0 ; out1i = m1 - t*r0
template<int MASK>
__device__ __forceinline__ void apply_rx_t(v2f (&re)[16], v2f (&im)[16], v2f t) {
#pragma unroll
    for (int i0 = 0; i0 < 16; ++i0) {
        if (i0 & MASK) continue;
        const int i1 = i0 | MASK;
        v2f r0 = re[i0], r1 = re[i1];
        v2f m0 = im[i0], m1 = im[i1];
        re[i0] = t * m1 + r0;
        im[i0] = m0 - t * r1;
        re[i1] = t * m0 + r1;
        im[i1] = m1 - t * r0;
    }
}

template<int CMASK, int TMASK>
__device__ __forceinline__ void apply_cnot(v2f (&re)[16], v2f (&im)[16]) {
#pragma unroll
    for (int i = 0; i < 16; ++i) {
        if ((i & CMASK) && !(i & TMASK)) {
            const int j = i | TMASK;
            v2f tr = re[i]; re[i] = re[j]; re[j] = tr;
            v2f ti = im[i]; im[i] = im[j]; im[j] = ti;
        }
    }
}

__global__ __launch_bounds__(256) void qdqn_kernel(
    const float* __restrict__ x,        // (B,4) fp32
    const float* __restrict__ weights,  // (5,4) fp32
    const float* __restrict__ Wm,       // (2,4) fp32
    const float* __restrict__ bv,       // (2,)  fp32
    float4* __restrict__ out,           // (B/2,4): two float2 outputs packed
    int Bh)                             // B/2 threads
{
    // ---- uniforms: tan(w/2) per gate + accumulated scale S = prod cos(w/2) ----
    float tw[20];
    float S = 1.0f;
    const float INV_4PI = 0.07957747154594767f;   // w/2 rad = w*(1/4pi) rev
#pragma unroll
    for (int k = 0; k < 20; ++k) {
        float rev = weights[k] * INV_4PI;         // uniform -> scalar load
        float c = __builtin_amdgcn_cosf(rev);
        float s = __builtin_amdgcn_sinf(rev);
        tw[k] = rfl(s * __builtin_amdgcn_rcpf(c));
        S *= c;
    }
    S = rfl(S);
    const float S2 = S * S;                       // probs scale by S^2
    float Wu[8];
#pragma unroll
    for (int k = 0; k < 8; ++k) Wu[k] = rfl(Wm[k] * S2);   // fold scale here
    const float b0u = rfl(bv[0]);
    const float b1u = rfl(bv[1]);

    const int t = blockIdx.x * blockDim.x + threadIdx.x;
    if (t >= Bh) return;

    // ---- load two consecutive samples, pack component-wise into v2f ----
    const float4 xA = ((const float4*)x)[2 * t];
    const float4 xB = ((const float4*)x)[2 * t + 1];
    v2f xv[4] = { (v2f){xA.x, xB.x}, (v2f){xA.y, xB.y},
                  (v2f){xA.z, xB.z}, (v2f){xA.w, xB.w} };

    // RY half-angle cos/sin: sin(xn*pi/2) = v_sin(xn*0.25 rev), |rev|<=0.25
    const float inv_bounds4[4] = { 0.25f / 4.8f, 0.25f / 4.0f, 0.25f / 0.418f, 0.25f / 4.0f };
    v2f rc[4], rs[4];
#pragma unroll
    for (int q = 0; q < 4; ++q) {
        v2f rev = xv[q] * splat(inv_bounds4[q]);
        float ra = fminf(fmaxf(rev.x, -0.25f), 0.25f);
        float rb = fminf(fmaxf(rev.y, -0.25f), 0.25f);
        rs[q] = (v2f){ __builtin_amdgcn_sinf(ra), __builtin_amdgcn_sinf(rb) };
        rc[q] = (v2f){ __builtin_amdgcn_cosf(ra), __builtin_amdgcn_cosf(rb) };
    }

    // ---- layer 0 (separable until first CNOT), RX part in tangent form ----
    // (1/cw)*RX(w)RY(a)|0> = (alpha, beta):
    //   alpha = (ca, -t*sa), beta = (sa, -t*ca)
    v2f ar[4], ai[4], br[4], bi[4];
#pragma unroll
    for (int q = 0; q < 4; ++q) {
        v2f tq = splat(tw[q]);
        ar[q] = rc[q];
        ai[q] = -(tq * rs[q]);
        br[q] = rs[q];
        bi[q] = -(tq * rc[q]);
    }
    // tensor product, wire 0 = MSB
    v2f t2r[4], t2i[4];
#pragma unroll
    for (int i = 0; i < 4; ++i) {
        v2f xr = (i & 2) ? br[0] : ar[0], xi = (i & 2) ? bi[0] : ai[0];
        v2f yr = (i & 1) ? br[1] : ar[1], yi = (i & 1) ? bi[1] : ai[1];
        t2r[i] = xr * yr - xi * yi;
        t2i[i] = xr * yi + xi * yr;
    }
    v2f t3r[8], t3i[8];
#pragma unroll
    for (int i = 0; i < 8; ++i) {
        v2f xr = t2r[i >> 1], xi = t2i[i >> 1];
        v2f yr = (i & 1) ? br[2] : ar[2], yi = (i & 1) ? bi[2] : ai[2];
        t3r[i] = xr * yr - xi * yi;
        t3i[i] = xr * yi + xi * yr;
    }
    v2f re[16], im[16];
#pragma unroll
    for (int i = 0; i < 16; ++i) {
        v2f xr = t3r[i >> 1], xi = t3i[i >> 1];
        v2f yr = (i & 1) ? br[3] : ar[3], yi = (i & 1) ? bi[3] : ai[3];
        re[i] = xr * yr - xi * yi;
        im[i] = xr * yi + xi * yr;
    }
    apply_cnot<8, 4>(re, im);
    apply_cnot<4, 2>(re, im);
    apply_cnot<2, 1>(re, im);
    apply_cnot<1, 8>(re, im);

    // ---- layers 1..4: RY standard, RX tangent form ----
#pragma unroll
    for (int l = 1; l < 5; ++l) {
        apply_ry<8>(re, im, rc[0], rs[0]);
        apply_ry<4>(re, im, rc[1], rs[1]);
        apply_ry<2>(re, im, rc[2], rs[2]);
        apply_ry<1>(re, im, rc[3], rs[3]);
        apply_rx_t<8>(re, im, splat(tw[l * 4 + 0]));
        apply_rx_t<4>(re, im, splat(tw[l * 4 + 1]));
        apply_rx_t<2>(re, im, splat(tw[l * 4 + 2]));
        apply_rx_t<1>(re, im, splat(tw[l * 4 + 3]));
        apply_cnot<8, 4>(re, im);
        apply_cnot<4, 2>(re, im);
        apply_cnot<2, 1>(re, im);
        apply_cnot<1, 8>(re, im);
    }

    // ---- probs -> <Z_q> sign tree -> linear layer (scale folded in Wu) ----
    v2f p[16];
#pragma unroll
    for (int i = 0; i < 16; ++i) p[i] = re[i] * re[i] + im[i] * im[i];
    v2f tt[8];
#pragma unroll
    for (int i = 0; i < 8; ++i) tt[i] = p[2 * i] + p[2 * i + 1];
    v2f u[4];
#pragma unroll
    for (int i = 0; i < 4; ++i) u[i] = tt[2 * i] + tt[2 * i + 1];
    const v2f z0 = (u[0] + u[1]) - (u[2] + u[3]);               // wire 0 (bit 3)
    const v2f z1 = (u[0] - u[1]) + (u[2] - u[3]);               // wire 1 (bit 2)
    const v2f z2 = (tt[0] - tt[1]) + (tt[2] - tt[3])
                 + (tt[4] - tt[5]) + (tt[6] - tt[7]);           // wire 2 (bit 1)
    const v2f z3 = ((p[0] - p[1]) + (p[2] - p[3]))
                 + ((p[4] - p[5]) + (p[6] - p[7]))
                 + ((p[8] - p[9]) + (p[10] - p[11]))
                 + ((p[12] - p[13]) + (p[14] - p[15]));         // wire 3 (bit 0)

    v2f o0 = splat(b0u), o1 = splat(b1u);
    o0 = splat(Wu[0]) * z0 + o0; o0 = splat(Wu[1]) * z1 + o0;
    o0 = splat(Wu[2]) * z2 + o0; o0 = splat(Wu[3]) * z3 + o0;
    o1 = splat(Wu[4]) * z0 + o1; o1 = splat(Wu[5]) * z1 + o1;
    o1 = splat(Wu[6]) * z2 + o1; o1 = splat(Wu[7]) * z3 + o1;

    out[t] = make_float4(o0.x, o1.x, o0.y, o1.y);   // 16B coalesced store
}

extern "C" void kernel_launch(void* const* d_in, const int* in_sizes, int n_in,
                              void* d_out, int out_size, void* d_ws, size_t ws_size,
                              hipStream_t stream) {
    const float* x  = (const float*)d_in[0];
    const float* w  = (const float*)d_in[1];
    const float* Wm = (const float*)d_in[2];
    const float* bv = (const float*)d_in[3];
    float4* out = (float4*)d_out;

    const int B  = in_sizes[0] / 4;
    const int Bh = B / 2;                       // B is even (524288)
    dim3 grid((Bh + 255) / 256), block(256);
    qdqn_kernel<<<grid, block, 0, stream>>>(x, w, Wm, bv, out, Bh);
}